// Round 1
// baseline (463.134 us; speedup 1.0000x reference)
//
#include <hip/hip_runtime.h>
#include <cstdint>
#include <cstddef>

// Problem constants
#define DMODEL 1024
#define HEADS  16
#define DHEAD  64
#define BATCH  4
#define SEQ    2048
#define ROWS   (BATCH * SEQ)          // 8192
#define INV_DSCALE 0.3535533905932738f // 1 / 64^(1/4)

typedef float  f32x4  __attribute__((ext_vector_type(4)));
typedef __bf16 bf16x8 __attribute__((ext_vector_type(8)));

__device__ __forceinline__ unsigned short f2bf(float x) {
    union { float f; unsigned u; } c; c.f = x;
    unsigned u = c.u;
    unsigned r = (u + 0x7fffu + ((u >> 16) & 1u)) >> 16;
    return (unsigned short)r;
}

__device__ __forceinline__ void load_g2l16(const unsigned short* g, unsigned short* l) {
    __builtin_amdgcn_global_load_lds(
        (const __attribute__((address_space(1))) unsigned int*)g,
        (__attribute__((address_space(3))) unsigned int*)l,
        16 /*bytes*/, 0 /*offset*/, 0 /*aux*/);
}

// ---------------------------------------------------------------------------
// Cast fp32 -> bf16, vectorized (n4 = number of float4 groups)
__global__ __launch_bounds__(256) void cast_bf16(const float4* __restrict__ X,
                                                 ushort4* __restrict__ Y, int n4) {
    int i = blockIdx.x * 256 + threadIdx.x;
    if (i < n4) {
        float4 v = X[i];
        ushort4 o;
        o.x = f2bf(v.x); o.y = f2bf(v.y); o.z = f2bf(v.z); o.w = f2bf(v.w);
        Y[i] = o;
    }
}

// Pack W[h][m][d] fp32 -> Wt[n = h*64+d][k = m] bf16  (N x K, K contiguous)
__global__ __launch_bounds__(256) void pack_w(const float* __restrict__ W,
                                              unsigned short* __restrict__ Wt) {
    int idx = blockIdx.x * 256 + threadIdx.x;   // 0 .. 1048575
    int n = idx >> 10, m = idx & 1023;
    int h = n >> 6,  d = n & 63;
    Wt[idx] = f2bf(W[((size_t)h * DMODEL + m) * DHEAD + d]);
}

// ---------------------------------------------------------------------------
// C[M,N] (fp32) = A[M,K] (bf16, row-major) * B^T where B is [N,K] (bf16, K contig)
// 128x128 tile, BK=32, 4 waves each computing 64x64 via 4x4 of 16x16x32 MFMA.
__global__ __launch_bounds__(256) void gemm_bt(const unsigned short* __restrict__ A,
                                               const unsigned short* __restrict__ B,
                                               float* __restrict__ C,
                                               int M, int N, int K) {
    __shared__ unsigned short ldsA[128 * 32];
    __shared__ unsigned short ldsB[128 * 32];

    const int t    = threadIdx.x;
    const int lane = t & 63;
    const int wave = t >> 6;
    const int bm0  = blockIdx.x * 128;
    const int bn0  = blockIdx.y * 128;
    const int wm   = (wave & 1) * 64;
    const int wn   = (wave >> 1) * 64;
    const int fr   = lane & 15;
    const int quad = lane >> 4;

    // staging: thread t loads 16B (8 bf16) at row = t/4, kofs = (t%4)*8, twice (row, row+64)
    const int row = t >> 2;
    const int ko  = (t & 3) * 8;

    f32x4 acc[4][4] = {};

    const unsigned short* gA0 = A + (size_t)(bm0 + row)      * K + ko;
    const unsigned short* gA1 = A + (size_t)(bm0 + row + 64) * K + ko;
    const unsigned short* gB0 = B + (size_t)(bn0 + row)      * K + ko;
    const unsigned short* gB1 = B + (size_t)(bn0 + row + 64) * K + ko;

    for (int k0 = 0; k0 < K; k0 += 32) {
        load_g2l16(gA0 + k0, &ldsA[row * 32 + ko]);
        load_g2l16(gA1 + k0, &ldsA[(row + 64) * 32 + ko]);
        load_g2l16(gB0 + k0, &ldsB[row * 32 + ko]);
        load_g2l16(gB1 + k0, &ldsB[(row + 64) * 32 + ko]);
        asm volatile("s_waitcnt vmcnt(0)" ::: "memory");
        __syncthreads();

        bf16x8 af[4], bfr[4];
        #pragma unroll
        for (int i = 0; i < 4; ++i)
            af[i] = *reinterpret_cast<const bf16x8*>(&ldsA[(wm + i * 16 + fr) * 32 + quad * 8]);
        #pragma unroll
        for (int j = 0; j < 4; ++j)
            bfr[j] = *reinterpret_cast<const bf16x8*>(&ldsB[(wn + j * 16 + fr) * 32 + quad * 8]);

        #pragma unroll
        for (int i = 0; i < 4; ++i)
            #pragma unroll
            for (int j = 0; j < 4; ++j)
                acc[i][j] = __builtin_amdgcn_mfma_f32_16x16x32_bf16(af[i], bfr[j], acc[i][j], 0, 0, 0);

        __syncthreads();
    }

    // C/D layout: col = lane&15, row = quad*4 + reg
    #pragma unroll
    for (int i = 0; i < 4; ++i)
        #pragma unroll
        for (int j = 0; j < 4; ++j)
            #pragma unroll
            for (int r = 0; r < 4; ++r) {
                int rr = bm0 + wm + i * 16 + quad * 4 + r;
                int cc = bn0 + wn + j * 16 + fr;
                C[(size_t)rr * N + cc] = acc[i][j][r];
            }
}

// ---------------------------------------------------------------------------
// In-place softmax over contiguous 64-element rows (one wave per row), input scaled.
__global__ __launch_bounds__(256) void softmax64(float* __restrict__ X) {
    int rowb = blockIdx.x * 4 + (threadIdx.x >> 6);
    int lane = threadIdx.x & 63;
    float* p = X + (size_t)rowb * 64;
    float v = p[lane] * INV_DSCALE;
    float m = v;
    #pragma unroll
    for (int off = 32; off; off >>= 1) m = fmaxf(m, __shfl_xor(m, off, 64));
    float e = __expf(v - m);
    float s = e;
    #pragma unroll
    for (int off = 32; off; off >>= 1) s += __shfl_xor(s, off, 64);
    p[lane] = e / s;
}

__global__ __launch_bounds__(256) void zero_f32(float4* __restrict__ p, int n4) {
    int i = blockIdx.x * 256 + threadIdx.x;
    if (i < n4) p[i] = make_float4(0.f, 0.f, 0.f, 0.f);
}

// ---------------------------------------------------------------------------
// A[bh][d][e] += sum_s Kp[b,s,h,d] * V[b,s,h,e]   (fp32, split-S with atomics)
// grid: bh*4 + chunk (chunk covers 512 s in 4 LDS tiles of 128)
__global__ __launch_bounds__(256) void kv_outer(const float* __restrict__ Kp,
                                                const float* __restrict__ V,
                                                float* __restrict__ A) {
    __shared__ float sk[128][64];
    __shared__ float sv[128][64];
    int bh = blockIdx.x >> 2, chunk = blockIdx.x & 3;
    int b = bh >> 4, h = bh & 15;
    int t = threadIdx.x;
    int d = t & 63, eg = t >> 6;
    int e0 = eg * 16;
    float acc[16];
    #pragma unroll
    for (int j = 0; j < 16; ++j) acc[j] = 0.f;

    for (int sc = 0; sc < 4; ++sc) {
        int s0 = chunk * 512 + sc * 128;
        #pragma unroll
        for (int i = 0; i < 8; ++i) {
            int f = t + 256 * i;        // float4 slot, 2048 total
            int r = f >> 4;
            int c = (f & 15) * 4;
            size_t g = (size_t)(b * SEQ + s0 + r) * DMODEL + h * DHEAD + c;
            *(float4*)&sk[r][c] = *(const float4*)&Kp[g];
            *(float4*)&sv[r][c] = *(const float4*)&V[g];
        }
        __syncthreads();
        for (int s = 0; s < 128; ++s) {
            float kd = sk[s][d];
            float4 v0 = *(const float4*)&sv[s][e0];
            float4 v1 = *(const float4*)&sv[s][e0 + 4];
            float4 v2 = *(const float4*)&sv[s][e0 + 8];
            float4 v3 = *(const float4*)&sv[s][e0 + 12];
            acc[0]  += kd * v0.x; acc[1]  += kd * v0.y; acc[2]  += kd * v0.z; acc[3]  += kd * v0.w;
            acc[4]  += kd * v1.x; acc[5]  += kd * v1.y; acc[6]  += kd * v1.z; acc[7]  += kd * v1.w;
            acc[8]  += kd * v2.x; acc[9]  += kd * v2.y; acc[10] += kd * v2.z; acc[11] += kd * v2.w;
            acc[12] += kd * v3.x; acc[13] += kd * v3.y; acc[14] += kd * v3.z; acc[15] += kd * v3.w;
        }
        __syncthreads();
    }
    float* Abh = A + (size_t)bh * 4096;
    #pragma unroll
    for (int j = 0; j < 16; ++j) atomicAdd(&Abh[d * 64 + e0 + j], acc[j]);
}

// ---------------------------------------------------------------------------
// Bt[b,h,s,e] = sum_d Qs[b,s,h,d] * A[bh][d][e], written bf16 in [b,h,s,e] flat order.
// grid: bh*32 + sb  (sb covers 64 s rows)
__global__ __launch_bounds__(256) void qs_a(const float* __restrict__ Qs,
                                            const float* __restrict__ A,
                                            unsigned short* __restrict__ R) {
    __shared__ float sA[64][64];
    __shared__ float sQ[64][64];
    int bh = blockIdx.x >> 5, sb = blockIdx.x & 31;
    int b = bh >> 4, h = bh & 15;
    int t = threadIdx.x;
    #pragma unroll
    for (int i = 0; i < 4; ++i) {
        int f = t + 256 * i;            // float4 slot, 1024 total
        int r = f >> 4;
        int c = (f & 15) * 4;
        *(float4*)&sA[r][c] = *(const float4*)&A[(size_t)bh * 4096 + (size_t)f * 4];
        *(float4*)&sQ[r][c] = *(const float4*)&Qs[(size_t)(b * SEQ + sb * 64 + r) * DMODEL + h * DHEAD + c];
    }
    __syncthreads();
    int lane = t & 63, w = t >> 6;
    for (int rr = 0; rr < 16; ++rr) {
        int r = w * 16 + rr;
        float acc = 0.f;
        #pragma unroll
        for (int d2 = 0; d2 < 64; ++d2) acc += sQ[r][d2] * sA[d2][lane];
        int s = sb * 64 + r;
        R[(size_t)bh * (SEQ * DHEAD) + (size_t)s * DHEAD + lane] = f2bf(acc);
    }
}

// ---------------------------------------------------------------------------
extern "C" void kernel_launch(void* const* d_in, const int* in_sizes, int n_in,
                              void* d_out, int out_size, void* d_ws, size_t ws_size,
                              hipStream_t stream) {
    const float* xq = (const float*)d_in[0];
    const float* xk = (const float*)d_in[1];
    const float* xv = (const float*)d_in[2];
    const float* Wq = (const float*)d_in[3];
    const float* Wk = (const float*)d_in[4];
    const float* Wv = (const float*)d_in[5];
    const float* Wo = (const float*)d_in[6];
    float* out = (float*)d_out;
    char* ws = (char*)d_ws;

    const size_t MB = 1ull << 20;
    unsigned short* wq_t = (unsigned short*)(ws + 0 * MB);    // 2 MB each
    unsigned short* wk_t = (unsigned short*)(ws + 2 * MB);
    unsigned short* wv_t = (unsigned short*)(ws + 4 * MB);
    unsigned short* wo_b = (unsigned short*)(ws + 6 * MB);
    unsigned short* xq_b = (unsigned short*)(ws + 8 * MB);    // 16 MB each
    unsigned short* xk_b = (unsigned short*)(ws + 24 * MB);
    unsigned short* xv_b = (unsigned short*)(ws + 40 * MB);
    float* Q  = (float*)(ws + 56 * MB);                       // 32 MB each
    float* Km = (float*)(ws + 88 * MB);
    float* V  = (float*)(ws + 120 * MB);
    float* Am = (float*)(ws + 152 * MB);                      // 1 MB
    unsigned short* R = (unsigned short*)(ws + 153 * MB);     // 16 MB

    // weights -> bf16 (packed N x K)
    pack_w<<<4096, 256, 0, stream>>>(Wq, wq_t);
    pack_w<<<4096, 256, 0, stream>>>(Wk, wk_t);
    pack_w<<<4096, 256, 0, stream>>>(Wv, wv_t);
    cast_bf16<<<1024, 256, 0, stream>>>((const float4*)Wo, (ushort4*)wo_b, (DMODEL * DMODEL) / 4);

    // activations -> bf16
    cast_bf16<<<8192, 256, 0, stream>>>((const float4*)xq, (ushort4*)xq_b, (ROWS * DMODEL) / 4);
    cast_bf16<<<8192, 256, 0, stream>>>((const float4*)xk, (ushort4*)xk_b, (ROWS * DMODEL) / 4);
    cast_bf16<<<8192, 256, 0, stream>>>((const float4*)xv, (ushort4*)xv_b, (ROWS * DMODEL) / 4);

    // projections: [8192,1024] x [1024,1024]^T -> fp32
    dim3 gg(ROWS / 128, DMODEL / 128);
    gemm_bt<<<gg, 256, 0, stream>>>(xq_b, wq_t, Q,  ROWS, DMODEL, DMODEL);
    gemm_bt<<<gg, 256, 0, stream>>>(xk_b, wk_t, Km, ROWS, DMODEL, DMODEL);
    gemm_bt<<<gg, 256, 0, stream>>>(xv_b, wv_t, V,  ROWS, DMODEL, DMODEL);

    // softmax over head-dim (64) for Q and K, in place, fp32
    softmax64<<<(ROWS * HEADS) / 4, 256, 0, stream>>>(Q);
    softmax64<<<(ROWS * HEADS) / 4, 256, 0, stream>>>(Km);

    // A = softmax(K)^T V per (b,h): zero then split-S atomic accumulate
    zero_f32<<<256, 256, 0, stream>>>((float4*)Am, (BATCH * HEADS * DHEAD * DHEAD) / 4);
    kv_outer<<<BATCH * HEADS * 4, 256, 0, stream>>>(Km, V, Am);

    // Bt = softmax(Q) A -> bf16 R in [b,h,s,d] flat order (== reference reshape)
    qs_a<<<BATCH * HEADS * 32, 256, 0, stream>>>(Q, Am, R);

    // out = R @ W_O^T
    gemm_bt<<<gg, 256, 0, stream>>>(R, wo_b, out, ROWS, DMODEL, DMODEL);
}

// Round 2
// 372.084 us; speedup vs baseline: 1.2447x; 1.2447x over previous
//
#include <hip/hip_runtime.h>
#include <cstdint>
#include <cstddef>

// Problem constants
#define DMODEL 1024
#define HEADS  16
#define DHEAD  64
#define BATCH  4
#define SEQ    2048
#define ROWS   (BATCH * SEQ)          // 8192
#define INV_DSCALE 0.3535533905932738f // 1 / 64^(1/4)

typedef float  f32x4  __attribute__((ext_vector_type(4)));
typedef __bf16 bf16x8 __attribute__((ext_vector_type(8)));

__device__ __forceinline__ unsigned short f2bf(float x) {
    union { float f; unsigned u; } c; c.f = x;
    unsigned u = c.u;
    unsigned r = (u + 0x7fffu + ((u >> 16) & 1u)) >> 16;
    return (unsigned short)r;
}

__device__ __forceinline__ void load_g2l16(const unsigned short* g, unsigned short* l) {
    __builtin_amdgcn_global_load_lds(
        (const __attribute__((address_space(1))) unsigned int*)g,
        (__attribute__((address_space(3))) unsigned int*)l,
        16 /*bytes*/, 0 /*offset*/, 0 /*aux*/);
}

// ---------------------------------------------------------------------------
// Cast fp32 -> bf16, vectorized (n4 = number of float4 groups)
__global__ __launch_bounds__(256) void cast_bf16(const float4* __restrict__ X,
                                                 ushort4* __restrict__ Y, int n4) {
    int i = blockIdx.x * 256 + threadIdx.x;
    if (i < n4) {
        float4 v = X[i];
        ushort4 o;
        o.x = f2bf(v.x); o.y = f2bf(v.y); o.z = f2bf(v.z); o.w = f2bf(v.w);
        Y[i] = o;
    }
}

// Pack W[h][m][d] fp32 -> Wt[n = h*64+d][k = m] bf16  (N x K, K contiguous)
__global__ __launch_bounds__(256) void pack_w(const float* __restrict__ W,
                                              unsigned short* __restrict__ Wt) {
    int idx = blockIdx.x * 256 + threadIdx.x;   // 0 .. 1048575
    int n = idx >> 10, m = idx & 1023;
    int h = n >> 6,  d = n & 63;
    Wt[idx] = f2bf(W[((size_t)h * DMODEL + m) * DHEAD + d]);
}

// ---------------------------------------------------------------------------
// C[M,N] (fp32) = A[M,K] (bf16, row-major) * B^T where B is [N,K] (bf16, K contig)
// 128x128 tile, BK=32, 4 waves each computing 64x64 via 4x4 of 16x16x32 MFMA.
// SM: fuse softmax over each 64-wide head group of the output row (cols are
// head-aligned since bn0+wn is a multiple of 64 and j*16+fr spans exactly 64).
template <bool SM>
__global__ __launch_bounds__(256) void gemm_bt(const unsigned short* __restrict__ A,
                                               const unsigned short* __restrict__ B,
                                               float* __restrict__ C,
                                               int M, int N, int K) {
    __shared__ unsigned short ldsA[128 * 32];
    __shared__ unsigned short ldsB[128 * 32];

    const int t    = threadIdx.x;
    const int lane = t & 63;
    const int wave = t >> 6;
    const int bm0  = blockIdx.x * 128;
    const int bn0  = blockIdx.y * 128;
    const int wm   = (wave & 1) * 64;
    const int wn   = (wave >> 1) * 64;
    const int fr   = lane & 15;
    const int quad = lane >> 4;

    const int row = t >> 2;
    const int ko  = (t & 3) * 8;

    f32x4 acc[4][4] = {};

    const unsigned short* gA0 = A + (size_t)(bm0 + row)      * K + ko;
    const unsigned short* gA1 = A + (size_t)(bm0 + row + 64) * K + ko;
    const unsigned short* gB0 = B + (size_t)(bn0 + row)      * K + ko;
    const unsigned short* gB1 = B + (size_t)(bn0 + row + 64) * K + ko;

    for (int k0 = 0; k0 < K; k0 += 32) {
        load_g2l16(gA0 + k0, &ldsA[row * 32 + ko]);
        load_g2l16(gA1 + k0, &ldsA[(row + 64) * 32 + ko]);
        load_g2l16(gB0 + k0, &ldsB[row * 32 + ko]);
        load_g2l16(gB1 + k0, &ldsB[(row + 64) * 32 + ko]);
        asm volatile("s_waitcnt vmcnt(0)" ::: "memory");
        __syncthreads();

        bf16x8 af[4], bfr[4];
        #pragma unroll
        for (int i = 0; i < 4; ++i)
            af[i] = *reinterpret_cast<const bf16x8*>(&ldsA[(wm + i * 16 + fr) * 32 + quad * 8]);
        #pragma unroll
        for (int j = 0; j < 4; ++j)
            bfr[j] = *reinterpret_cast<const bf16x8*>(&ldsB[(wn + j * 16 + fr) * 32 + quad * 8]);

        #pragma unroll
        for (int i = 0; i < 4; ++i)
            #pragma unroll
            for (int j = 0; j < 4; ++j)
                acc[i][j] = __builtin_amdgcn_mfma_f32_16x16x32_bf16(af[i], bfr[j], acc[i][j], 0, 0, 0);

        __syncthreads();
    }

    // C/D layout: col = lane&15 (fr), row = quad*4 + reg
    #pragma unroll
    for (int i = 0; i < 4; ++i) {
        #pragma unroll
        for (int r = 0; r < 4; ++r) {
            float v[4];
            #pragma unroll
            for (int j = 0; j < 4; ++j) v[j] = acc[i][j][r];
            if (SM) {
                #pragma unroll
                for (int j = 0; j < 4; ++j) v[j] *= INV_DSCALE;
                float m = fmaxf(fmaxf(v[0], v[1]), fmaxf(v[2], v[3]));
                #pragma unroll
                for (int off = 8; off; off >>= 1) m = fmaxf(m, __shfl_xor(m, off, 16));
                float s = 0.f;
                #pragma unroll
                for (int j = 0; j < 4; ++j) { v[j] = __expf(v[j] - m); s += v[j]; }
                #pragma unroll
                for (int off = 8; off; off >>= 1) s += __shfl_xor(s, off, 16);
                float inv = 1.0f / s;
                #pragma unroll
                for (int j = 0; j < 4; ++j) v[j] *= inv;
            }
            int rr = bm0 + wm + i * 16 + quad * 4 + r;
            size_t base = (size_t)rr * N + bn0 + wn + fr;
            #pragma unroll
            for (int j = 0; j < 4; ++j) C[base + j * 16] = v[j];
        }
    }
}

// ---------------------------------------------------------------------------
// P[chunk][bh][d][e] = sum over 128 s of Ks[b,s,h,d] * V[b,s,h,e]  (fp32)
// grid: bh*16 + chunk (1024 blocks); 32 KB LDS -> ~4 blocks/CU.
__global__ __launch_bounds__(256) void kv_outer(const float* __restrict__ Ks,
                                                const float* __restrict__ V,
                                                float* __restrict__ P) {
    __shared__ float sk[64][64];
    __shared__ float sv[64][64];
    int bh = blockIdx.x >> 4, chunk = blockIdx.x & 15;
    int b = bh >> 4, h = bh & 15;
    int t = threadIdx.x;
    int d = t & 63, eg = t >> 6;
    int e0 = eg * 16;
    float acc[16];
    #pragma unroll
    for (int j = 0; j < 16; ++j) acc[j] = 0.f;

    for (int sc = 0; sc < 2; ++sc) {
        int s0 = chunk * 128 + sc * 64;
        #pragma unroll
        for (int i = 0; i < 4; ++i) {
            int f = t + 256 * i;        // float4 slot, 1024 total
            int r = f >> 4;
            int c = (f & 15) * 4;
            size_t g = (size_t)(b * SEQ + s0 + r) * DMODEL + h * DHEAD + c;
            *(float4*)&sk[r][c] = *(const float4*)&Ks[g];
            *(float4*)&sv[r][c] = *(const float4*)&V[g];
        }
        __syncthreads();
        #pragma unroll 8
        for (int s = 0; s < 64; ++s) {
            float kd = sk[s][d];
            float4 v0 = *(const float4*)&sv[s][e0];
            float4 v1 = *(const float4*)&sv[s][e0 + 4];
            float4 v2 = *(const float4*)&sv[s][e0 + 8];
            float4 v3 = *(const float4*)&sv[s][e0 + 12];
            acc[0]  += kd * v0.x; acc[1]  += kd * v0.y; acc[2]  += kd * v0.z; acc[3]  += kd * v0.w;
            acc[4]  += kd * v1.x; acc[5]  += kd * v1.y; acc[6]  += kd * v1.z; acc[7]  += kd * v1.w;
            acc[8]  += kd * v2.x; acc[9]  += kd * v2.y; acc[10] += kd * v2.z; acc[11] += kd * v2.w;
            acc[12] += kd * v3.x; acc[13] += kd * v3.y; acc[14] += kd * v3.z; acc[15] += kd * v3.w;
        }
        __syncthreads();
    }
    float* Pp = P + ((size_t)chunk * 64 + bh) * 4096 + d * 64 + e0;
    #pragma unroll
    for (int j = 0; j < 16; j += 4)
        *(float4*)&Pp[j] = make_float4(acc[j], acc[j + 1], acc[j + 2], acc[j + 3]);
}

// A[idx] = sum over 16 chunks of P[chunk][idx], idx in [0, 64*4096)
__global__ __launch_bounds__(256) void reduce_A(const float* __restrict__ P,
                                                float* __restrict__ A) {
    int idx = blockIdx.x * 256 + threadIdx.x;   // 0 .. 262143
    float s = 0.f;
    #pragma unroll
    for (int c = 0; c < 16; ++c) s += P[(size_t)c * (64 * 4096) + idx];
    A[idx] = s;
}

// ---------------------------------------------------------------------------
// Bt[b,h,s,e] = sum_d Qs[b,s,h,d] * A[bh][d][e], written bf16 in [b,h,s,e] flat order.
// grid: bh*32 + sb  (sb covers 64 s rows)
__global__ __launch_bounds__(256) void qs_a(const float* __restrict__ Qs,
                                            const float* __restrict__ A,
                                            unsigned short* __restrict__ R) {
    __shared__ float sA[64][64];
    __shared__ float sQ[64][64];
    int bh = blockIdx.x >> 5, sb = blockIdx.x & 31;
    int b = bh >> 4, h = bh & 15;
    int t = threadIdx.x;
    #pragma unroll
    for (int i = 0; i < 4; ++i) {
        int f = t + 256 * i;            // float4 slot, 1024 total
        int r = f >> 4;
        int c = (f & 15) * 4;
        *(float4*)&sA[r][c] = *(const float4*)&A[(size_t)bh * 4096 + (size_t)f * 4];
        *(float4*)&sQ[r][c] = *(const float4*)&Qs[(size_t)(b * SEQ + sb * 64 + r) * DMODEL + h * DHEAD + c];
    }
    __syncthreads();
    int lane = t & 63, w = t >> 6;
    float acc[16];
    #pragma unroll
    for (int r = 0; r < 16; ++r) acc[r] = 0.f;
    for (int d2 = 0; d2 < 64; d2 += 4) {
        float a0 = sA[d2][lane], a1 = sA[d2 + 1][lane];
        float a2 = sA[d2 + 2][lane], a3 = sA[d2 + 3][lane];
        #pragma unroll
        for (int r = 0; r < 16; ++r) {
            float4 q4 = *(const float4*)&sQ[w * 16 + r][d2];   // wave-broadcast
            acc[r] += q4.x * a0 + q4.y * a1 + q4.z * a2 + q4.w * a3;
        }
    }
    size_t base = (size_t)bh * (SEQ * DHEAD) + (size_t)(sb * 64 + w * 16) * DHEAD + lane;
    #pragma unroll
    for (int r = 0; r < 16; ++r) R[base + (size_t)r * DHEAD] = f2bf(acc[r]);
}

// ---------------------------------------------------------------------------
extern "C" void kernel_launch(void* const* d_in, const int* in_sizes, int n_in,
                              void* d_out, int out_size, void* d_ws, size_t ws_size,
                              hipStream_t stream) {
    const float* xq = (const float*)d_in[0];
    const float* xk = (const float*)d_in[1];
    const float* xv = (const float*)d_in[2];
    const float* Wq = (const float*)d_in[3];
    const float* Wk = (const float*)d_in[4];
    const float* Wv = (const float*)d_in[5];
    const float* Wo = (const float*)d_in[6];
    float* out = (float*)d_out;
    char* ws = (char*)d_ws;

    const size_t MB = 1ull << 20;
    unsigned short* wq_t = (unsigned short*)(ws + 0 * MB);    // 2 MB each
    unsigned short* wk_t = (unsigned short*)(ws + 2 * MB);
    unsigned short* wv_t = (unsigned short*)(ws + 4 * MB);
    unsigned short* wo_b = (unsigned short*)(ws + 6 * MB);
    unsigned short* xq_b = (unsigned short*)(ws + 8 * MB);    // 16 MB each
    unsigned short* xk_b = (unsigned short*)(ws + 24 * MB);
    unsigned short* xv_b = (unsigned short*)(ws + 40 * MB);
    float* Q  = (float*)(ws + 56 * MB);                       // 32 MB each
    float* Km = (float*)(ws + 88 * MB);
    float* V  = (float*)(ws + 120 * MB);
    float* Am = (float*)(ws + 152 * MB);                      // 1 MB
    unsigned short* R = (unsigned short*)(ws + 153 * MB);     // 16 MB
    // P (16 MB of fp32 partials) reuses xq_b's slot: xq_b is dead after the
    // Q projection GEMM, and kv_outer runs strictly after all three GEMMs.
    float* P = (float*)(ws + 8 * MB);

    // weights -> bf16 (packed N x K)
    pack_w<<<4096, 256, 0, stream>>>(Wq, wq_t);
    pack_w<<<4096, 256, 0, stream>>>(Wk, wk_t);
    pack_w<<<4096, 256, 0, stream>>>(Wv, wv_t);
    cast_bf16<<<1024, 256, 0, stream>>>((const float4*)Wo, (ushort4*)wo_b, (DMODEL * DMODEL) / 4);

    // activations -> bf16
    cast_bf16<<<8192, 256, 0, stream>>>((const float4*)xq, (ushort4*)xq_b, (ROWS * DMODEL) / 4);
    cast_bf16<<<8192, 256, 0, stream>>>((const float4*)xk, (ushort4*)xk_b, (ROWS * DMODEL) / 4);
    cast_bf16<<<8192, 256, 0, stream>>>((const float4*)xv, (ushort4*)xv_b, (ROWS * DMODEL) / 4);

    // projections: [8192,1024] x [1024,1024]^T -> fp32; softmax fused for Q,K
    dim3 gg(ROWS / 128, DMODEL / 128);
    gemm_bt<true ><<<gg, 256, 0, stream>>>(xq_b, wq_t, Q,  ROWS, DMODEL, DMODEL);
    gemm_bt<true ><<<gg, 256, 0, stream>>>(xk_b, wk_t, Km, ROWS, DMODEL, DMODEL);
    gemm_bt<false><<<gg, 256, 0, stream>>>(xv_b, wv_t, V,  ROWS, DMODEL, DMODEL);

    // A = softmax(K)^T V per (b,h): split-S partials then deterministic reduce
    kv_outer<<<BATCH * HEADS * 16, 256, 0, stream>>>(Km, V, P);
    reduce_A<<<1024, 256, 0, stream>>>(P, Am);

    // Bt = softmax(Q) A -> bf16 R in [b,h,s,d] flat order (== reference reshape)
    qs_a<<<BATCH * HEADS * 32, 256, 0, stream>>>(Q, Am, R);

    // out = R @ W_O^T
    gemm_bt<false><<<gg, 256, 0, stream>>>(R, wo_b, out, ROWS, DMODEL, DMODEL);
}

// Round 3
// 308.584 us; speedup vs baseline: 1.5008x; 1.2058x over previous
//
#include <hip/hip_runtime.h>
#include <cstdint>
#include <cstddef>

// Problem constants
#define DMODEL 1024
#define HEADS  16
#define DHEAD  64
#define BATCH  4
#define SEQ    2048
#define ROWS   (BATCH * SEQ)          // 8192
#define INV_DSCALE 0.3535533905932738f // 1 / 64^(1/4)

typedef float  f32x4  __attribute__((ext_vector_type(4)));
typedef __bf16 bf16x8 __attribute__((ext_vector_type(8)));
typedef unsigned short u16x8 __attribute__((ext_vector_type(8)));

__device__ __forceinline__ unsigned short f2bf(float x) {
    union { float f; unsigned u; } c; c.f = x;
    unsigned u = c.u;
    return (unsigned short)((u + 0x7fffu + ((u >> 16) & 1u)) >> 16);
}
__device__ __forceinline__ float bf2f(unsigned short h) {
    union { unsigned u; float f; } c; c.u = ((unsigned)h) << 16;
    return c.f;
}

__device__ __forceinline__ void load_g2l16(const unsigned short* g, unsigned short* l) {
    __builtin_amdgcn_global_load_lds(
        (const __attribute__((address_space(1))) unsigned int*)g,
        (__attribute__((address_space(3))) unsigned int*)l,
        16 /*bytes*/, 0 /*offset*/, 0 /*aux*/);
}

// ---------------------------------------------------------------------------
// Cast fp32 -> bf16, vectorized (n4 = number of float4 groups)
__global__ __launch_bounds__(256) void cast_bf16(const float4* __restrict__ X,
                                                 ushort4* __restrict__ Y, int n4) {
    int i = blockIdx.x * 256 + threadIdx.x;
    if (i < n4) {
        float4 v = X[i];
        ushort4 o;
        o.x = f2bf(v.x); o.y = f2bf(v.y); o.z = f2bf(v.z); o.w = f2bf(v.w);
        Y[i] = o;
    }
}

// Cast the three activation tensors in one launch. 8192 blocks per tensor.
__global__ __launch_bounds__(256) void cast3(const float4* __restrict__ x0,
                                             const float4* __restrict__ x1,
                                             const float4* __restrict__ x2,
                                             ushort4* __restrict__ y0,
                                             ushort4* __restrict__ y1,
                                             ushort4* __restrict__ y2) {
    int which = blockIdx.x >> 13;
    int i = ((blockIdx.x & 8191) << 8) + threadIdx.x;   // < 2097152
    const float4* X = which == 0 ? x0 : (which == 1 ? x1 : x2);
    ushort4*      Y = which == 0 ? y0 : (which == 1 ? y1 : y2);
    float4 v = X[i];
    ushort4 o;
    o.x = f2bf(v.x); o.y = f2bf(v.y); o.z = f2bf(v.z); o.w = f2bf(v.w);
    Y[i] = o;
}

// Pack Wq/Wk/Wv [h][m][d] fp32 -> Wt[n = h*64+d][k = m] bf16 via LDS transpose.
// grid: 3 * 16 h * 16 mblocks = 768 blocks.
__global__ __launch_bounds__(256) void pack3(const float* __restrict__ W0,
                                             const float* __restrict__ W1,
                                             const float* __restrict__ W2,
                                             unsigned short* __restrict__ T0,
                                             unsigned short* __restrict__ T1,
                                             unsigned short* __restrict__ T2) {
    __shared__ float tile[64][68];
    int blk = blockIdx.x;
    int w = blk >> 8, h = (blk >> 4) & 15, mb = blk & 15;
    const float* W = w == 0 ? W0 : (w == 1 ? W1 : W2);
    unsigned short* T = w == 0 ? T0 : (w == 1 ? T1 : T2);
    int t = threadIdx.x;
    #pragma unroll
    for (int i = 0; i < 4; ++i) {
        int f = t + 256 * i;            // 0..1023
        int m = f >> 4, dg = (f & 15) * 4;
        *(float4*)&tile[m][dg] = *(const float4*)&W[((size_t)(h * 16 + mb) * 64 + m) * 64 + dg];
    }
    __syncthreads();
    #pragma unroll
    for (int i = 0; i < 2; ++i) {
        int f = t + 256 * i;            // 0..511
        int d = f >> 3, mg = f & 7;
        ushort4 a, b;
        a.x = f2bf(tile[mg * 8 + 0][d]); a.y = f2bf(tile[mg * 8 + 1][d]);
        a.z = f2bf(tile[mg * 8 + 2][d]); a.w = f2bf(tile[mg * 8 + 3][d]);
        b.x = f2bf(tile[mg * 8 + 4][d]); b.y = f2bf(tile[mg * 8 + 5][d]);
        b.z = f2bf(tile[mg * 8 + 6][d]); b.w = f2bf(tile[mg * 8 + 7][d]);
        unsigned short* dst = T + (size_t)(h * 64 + d) * DMODEL + mb * 64 + mg * 8;
        *(ushort4*)dst = a; *(ushort4*)(dst + 4) = b;
    }
}

// ---------------------------------------------------------------------------
// C[M,N] = A[M,K] (bf16 row-major) * B^T, B is [N,K] bf16 (K contiguous).
// 64x128 tile, BK=64, 4 waves each 32x64 via 2x4 of 16x16x32 MFMA.
// XOR swizzle: LDS slot (row, s) holds global k-group s ^ (row&7); frag read
// for logical kg uses slot kg ^ (row&7) -> start banks spread over fr.
// SM: fused softmax over each 64-wide head group (wn is a multiple of 64).
// OBF16: store bf16 instead of fp32.
template <bool SM, bool OBF16>
__global__ __launch_bounds__(256, 4) void gemm_bt(const unsigned short* __restrict__ A,
                                                  const unsigned short* __restrict__ B,
                                                  void* __restrict__ Cv,
                                                  int M, int N, int K) {
    __shared__ unsigned short ldsA[64 * 64];    // 8 KB
    __shared__ unsigned short ldsB[128 * 64];   // 16 KB

    const int t    = threadIdx.x;
    const int lane = t & 63;
    const int wave = t >> 6;
    const int bm0  = blockIdx.x * 64;
    const int bn0  = blockIdx.y * 128;
    const int wm   = (wave & 1) * 32;
    const int wn   = (wave >> 1) * 64;
    const int fr   = lane & 15;
    const int quad = lane >> 4;

    f32x4 acc[2][4] = {};

    // staging source pointers (global kg permuted by row&7; LDS dest linear in f)
    const unsigned short* gA[2];
    const unsigned short* gB[4];
    #pragma unroll
    for (int i = 0; i < 2; ++i) {
        int f = t + 256 * i, row = f >> 3, kg = (f & 7) ^ (row & 7);
        gA[i] = A + (size_t)(bm0 + row) * K + kg * 8;
    }
    #pragma unroll
    for (int i = 0; i < 4; ++i) {
        int f = t + 256 * i, row = f >> 3, kg = (f & 7) ^ (row & 7);
        gB[i] = B + (size_t)(bn0 + row) * K + kg * 8;
    }

    for (int k0 = 0; k0 < K; k0 += 64) {
        #pragma unroll
        for (int i = 0; i < 2; ++i)
            load_g2l16(gA[i] + k0, &ldsA[(t + 256 * i) * 8]);
        #pragma unroll
        for (int i = 0; i < 4; ++i)
            load_g2l16(gB[i] + k0, &ldsB[(t + 256 * i) * 8]);
        asm volatile("s_waitcnt vmcnt(0)" ::: "memory");
        __syncthreads();

        bf16x8 af[2][2], bfr[4][2];
        #pragma unroll
        for (int i = 0; i < 2; ++i) {
            int row = wm + i * 16 + fr;
            #pragma unroll
            for (int kh = 0; kh < 2; ++kh) {
                int s = (kh * 4 + quad) ^ (row & 7);
                af[i][kh] = *reinterpret_cast<const bf16x8*>(&ldsA[row * 64 + s * 8]);
            }
        }
        #pragma unroll
        for (int j = 0; j < 4; ++j) {
            int row = wn + j * 16 + fr;
            #pragma unroll
            for (int kh = 0; kh < 2; ++kh) {
                int s = (kh * 4 + quad) ^ (row & 7);
                bfr[j][kh] = *reinterpret_cast<const bf16x8*>(&ldsB[row * 64 + s * 8]);
            }
        }

        #pragma unroll
        for (int kh = 0; kh < 2; ++kh)
            #pragma unroll
            for (int i = 0; i < 2; ++i)
                #pragma unroll
                for (int j = 0; j < 4; ++j)
                    acc[i][j] = __builtin_amdgcn_mfma_f32_16x16x32_bf16(af[i][kh], bfr[j][kh], acc[i][j], 0, 0, 0);

        __syncthreads();
    }

    // C/D layout: col = lane&15 (fr), row = quad*4 + reg
    #pragma unroll
    for (int i = 0; i < 2; ++i) {
        #pragma unroll
        for (int r = 0; r < 4; ++r) {
            float v[4];
            #pragma unroll
            for (int j = 0; j < 4; ++j) v[j] = acc[i][j][r];
            if (SM) {
                #pragma unroll
                for (int j = 0; j < 4; ++j) v[j] *= INV_DSCALE;
                float m = fmaxf(fmaxf(v[0], v[1]), fmaxf(v[2], v[3]));
                #pragma unroll
                for (int off = 8; off; off >>= 1) m = fmaxf(m, __shfl_xor(m, off, 16));
                float s = 0.f;
                #pragma unroll
                for (int j = 0; j < 4; ++j) { v[j] = __expf(v[j] - m); s += v[j]; }
                #pragma unroll
                for (int off = 8; off; off >>= 1) s += __shfl_xor(s, off, 16);
                float inv = 1.0f / s;
                #pragma unroll
                for (int j = 0; j < 4; ++j) v[j] *= inv;
            }
            int rr = bm0 + wm + i * 16 + quad * 4 + r;
            size_t base = (size_t)rr * N + bn0 + wn + fr;
            if (OBF16) {
                unsigned short* C = (unsigned short*)Cv;
                #pragma unroll
                for (int j = 0; j < 4; ++j) C[base + j * 16] = f2bf(v[j]);
            } else {
                float* C = (float*)Cv;
                #pragma unroll
                for (int j = 0; j < 4; ++j) C[base + j * 16] = v[j];
            }
        }
    }
}

// ---------------------------------------------------------------------------
// P[chunk][bh][d][e] = sum over 128 s of Ks[b,s,h,d] * V[b,s,h,e]  (fp32 out,
// bf16 in). grid: bh*16 + chunk (1024 blocks), 32 KB LDS.
__global__ __launch_bounds__(256) void kv_outer(const unsigned short* __restrict__ Ks,
                                                const unsigned short* __restrict__ V,
                                                float* __restrict__ P) {
    __shared__ float sk[64][64];
    __shared__ float sv[64][64];
    int bh = blockIdx.x >> 4, chunk = blockIdx.x & 15;
    int b = bh >> 4, h = bh & 15;
    int t = threadIdx.x;
    int d = t & 63, eg = t >> 6;
    int e0 = eg * 16;
    float acc[16];
    #pragma unroll
    for (int j = 0; j < 16; ++j) acc[j] = 0.f;

    for (int sc = 0; sc < 2; ++sc) {
        int s0 = chunk * 128 + sc * 64;
        #pragma unroll
        for (int i = 0; i < 2; ++i) {
            int f = t + 256 * i;        // 0..511
            int r = f >> 3, c = (f & 7) * 8;
            size_t g = (size_t)(b * SEQ + s0 + r) * DMODEL + h * DHEAD + c;
            u16x8 kk = *(const u16x8*)&Ks[g];
            u16x8 vv = *(const u16x8*)&V[g];
            #pragma unroll
            for (int j = 0; j < 8; ++j) { sk[r][c + j] = bf2f(kk[j]); sv[r][c + j] = bf2f(vv[j]); }
        }
        __syncthreads();
        #pragma unroll 8
        for (int s = 0; s < 64; ++s) {
            float kd = sk[s][d];
            float4 v0 = *(const float4*)&sv[s][e0];
            float4 v1 = *(const float4*)&sv[s][e0 + 4];
            float4 v2 = *(const float4*)&sv[s][e0 + 8];
            float4 v3 = *(const float4*)&sv[s][e0 + 12];
            acc[0]  += kd * v0.x; acc[1]  += kd * v0.y; acc[2]  += kd * v0.z; acc[3]  += kd * v0.w;
            acc[4]  += kd * v1.x; acc[5]  += kd * v1.y; acc[6]  += kd * v1.z; acc[7]  += kd * v1.w;
            acc[8]  += kd * v2.x; acc[9]  += kd * v2.y; acc[10] += kd * v2.z; acc[11] += kd * v2.w;
            acc[12] += kd * v3.x; acc[13] += kd * v3.y; acc[14] += kd * v3.z; acc[15] += kd * v3.w;
        }
        __syncthreads();
    }
    float* Pp = P + ((size_t)chunk * 64 + bh) * 4096 + d * 64 + e0;
    #pragma unroll
    for (int j = 0; j < 16; j += 4)
        *(float4*)&Pp[j] = make_float4(acc[j], acc[j + 1], acc[j + 2], acc[j + 3]);
}

// A[idx] = sum over 16 chunks of P[chunk][idx], idx in [0, 64*4096)
__global__ __launch_bounds__(256) void reduce_A(const float* __restrict__ P,
                                                float* __restrict__ A) {
    int idx = blockIdx.x * 256 + threadIdx.x;   // 0 .. 262143
    float s = 0.f;
    #pragma unroll
    for (int c = 0; c < 16; ++c) s += P[(size_t)c * (64 * 4096) + idx];
    A[idx] = s;
}

// ---------------------------------------------------------------------------
// Bt[b,h,s,e] = sum_d Qs[b,s,h,d] * A[bh][d][e]; Qs bf16, A fp32; bf16 out in
// [b,h,s,e] flat order. grid: bh*32 + sb (sb covers 64 s rows)
__global__ __launch_bounds__(256) void qs_a(const unsigned short* __restrict__ Qs,
                                            const float* __restrict__ A,
                                            unsigned short* __restrict__ R) {
    __shared__ float sA[64][64];
    __shared__ float sQ[64][64];
    int bh = blockIdx.x >> 5, sb = blockIdx.x & 31;
    int b = bh >> 4, h = bh & 15;
    int t = threadIdx.x;
    #pragma unroll
    for (int i = 0; i < 4; ++i) {
        int f = t + 256 * i;            // float4 slot, 1024 total
        int r = f >> 4, c = (f & 15) * 4;
        *(float4*)&sA[r][c] = *(const float4*)&A[(size_t)bh * 4096 + (size_t)f * 4];
    }
    #pragma unroll
    for (int i = 0; i < 2; ++i) {
        int f = t + 256 * i;            // 0..511
        int r = f >> 3, c = (f & 7) * 8;
        u16x8 q = *(const u16x8*)&Qs[(size_t)(b * SEQ + sb * 64 + r) * DMODEL + h * DHEAD + c];
        #pragma unroll
        for (int j = 0; j < 8; ++j) sQ[r][c + j] = bf2f(q[j]);
    }
    __syncthreads();
    int lane = t & 63, w = t >> 6;
    float acc[16];
    #pragma unroll
    for (int r = 0; r < 16; ++r) acc[r] = 0.f;
    for (int d2 = 0; d2 < 64; d2 += 4) {
        float a0 = sA[d2][lane], a1 = sA[d2 + 1][lane];
        float a2 = sA[d2 + 2][lane], a3 = sA[d2 + 3][lane];
        #pragma unroll
        for (int r = 0; r < 16; ++r) {
            float4 q4 = *(const float4*)&sQ[w * 16 + r][d2];   // wave-broadcast
            acc[r] += q4.x * a0 + q4.y * a1 + q4.z * a2 + q4.w * a3;
        }
    }
    size_t base = (size_t)bh * (SEQ * DHEAD) + (size_t)(sb * 64 + w * 16) * DHEAD + lane;
    #pragma unroll
    for (int r = 0; r < 16; ++r) R[base + (size_t)r * DHEAD] = f2bf(acc[r]);
}

// ---------------------------------------------------------------------------
extern "C" void kernel_launch(void* const* d_in, const int* in_sizes, int n_in,
                              void* d_out, int out_size, void* d_ws, size_t ws_size,
                              hipStream_t stream) {
    const float* xq = (const float*)d_in[0];
    const float* xk = (const float*)d_in[1];
    const float* xv = (const float*)d_in[2];
    const float* Wq = (const float*)d_in[3];
    const float* Wk = (const float*)d_in[4];
    const float* Wv = (const float*)d_in[5];
    const float* Wo = (const float*)d_in[6];
    float* out = (float*)d_out;
    char* ws = (char*)d_ws;

    const size_t MB = 1ull << 20;
    unsigned short* wq_t = (unsigned short*)(ws + 0 * MB);    // 2 MB each
    unsigned short* wk_t = (unsigned short*)(ws + 2 * MB);
    unsigned short* wv_t = (unsigned short*)(ws + 4 * MB);
    unsigned short* wo_b = (unsigned short*)(ws + 6 * MB);
    unsigned short* xq_b = (unsigned short*)(ws + 8 * MB);    // 16 MB each
    unsigned short* xk_b = (unsigned short*)(ws + 24 * MB);
    unsigned short* xv_b = (unsigned short*)(ws + 40 * MB);
    unsigned short* Qb = (unsigned short*)(ws + 56 * MB);     // bf16, 16 MB each
    unsigned short* Kb = (unsigned short*)(ws + 72 * MB);
    unsigned short* Vb = (unsigned short*)(ws + 88 * MB);
    float* Am = (float*)(ws + 104 * MB);                      // 1 MB
    unsigned short* R = (unsigned short*)(ws + 105 * MB);     // 16 MB
    float* P = (float*)(ws + 121 * MB);                       // 16 MB

    // weights -> bf16 (Wq/Wk/Wv packed N x K via LDS transpose; Wo straight cast)
    pack3<<<768, 256, 0, stream>>>(Wq, Wk, Wv, wq_t, wk_t, wv_t);
    cast_bf16<<<1024, 256, 0, stream>>>((const float4*)Wo, (ushort4*)wo_b, (DMODEL * DMODEL) / 4);

    // activations -> bf16 (one launch)
    cast3<<<3 * 8192, 256, 0, stream>>>((const float4*)xq, (const float4*)xk, (const float4*)xv,
                                        (ushort4*)xq_b, (ushort4*)xk_b, (ushort4*)xv_b);

    // projections: [8192,1024] x [1024,1024]^T; softmax fused for Q,K; bf16 out
    dim3 gg(ROWS / 64, DMODEL / 128);
    gemm_bt<true,  true><<<gg, 256, 0, stream>>>(xq_b, wq_t, Qb, ROWS, DMODEL, DMODEL);
    gemm_bt<true,  true><<<gg, 256, 0, stream>>>(xk_b, wk_t, Kb, ROWS, DMODEL, DMODEL);
    gemm_bt<false, true><<<gg, 256, 0, stream>>>(xv_b, wv_t, Vb, ROWS, DMODEL, DMODEL);

    // A = softmax(K)^T V per (b,h): split-S partials then deterministic reduce
    kv_outer<<<BATCH * HEADS * 16, 256, 0, stream>>>(Kb, Vb, P);
    reduce_A<<<1024, 256, 0, stream>>>(P, Am);

    // Bt = softmax(Q) A -> bf16 R in [b,h,s,d] flat order (== reference reshape)
    qs_a<<<BATCH * HEADS * 32, 256, 0, stream>>>(Qb, Am, R);

    // out = R @ W_O^T  (fp32 out)
    gemm_bt<false, false><<<gg, 256, 0, stream>>>(R, wo_b, out, ROWS, DMODEL, DMODEL);
}

// Round 4
// 304.374 us; speedup vs baseline: 1.5216x; 1.0138x over previous
//
#include <hip/hip_runtime.h>
#include <cstdint>
#include <cstddef>

// Problem constants
#define DMODEL 1024
#define HEADS  16
#define DHEAD  64
#define BATCH  4
#define SEQ    2048
#define ROWS   (BATCH * SEQ)          // 8192
#define INV_DSCALE 0.3535533905932738f // 1 / 64^(1/4)

typedef float  f32x4  __attribute__((ext_vector_type(4)));
typedef __bf16 bf16x8 __attribute__((ext_vector_type(8)));
typedef unsigned short u16x8 __attribute__((ext_vector_type(8)));

__device__ __forceinline__ unsigned short f2bf(float x) {
    union { float f; unsigned u; } c; c.f = x;
    unsigned u = c.u;
    return (unsigned short)((u + 0x7fffu + ((u >> 16) & 1u)) >> 16);
}
__device__ __forceinline__ float bf2f(unsigned short h) {
    union { unsigned u; float f; } c; c.u = ((unsigned)h) << 16;
    return c.f;
}

// Pack two f32 -> packed 2x bf16 (RNE). gfx950 has v_cvt_pk_bf16_f32.
__device__ __forceinline__ unsigned cvt_pk_bf16(float a, float b) {
#if __has_builtin(__builtin_amdgcn_cvt_pk_bf16_f32)
    typedef __bf16 bf16x2_t __attribute__((ext_vector_type(2)));
    union { bf16x2_t v; unsigned u; } c;
    c.v = __builtin_amdgcn_cvt_pk_bf16_f32(a, b);
    return c.u;
#else
    return (unsigned)f2bf(a) | ((unsigned)f2bf(b) << 16);
#endif
}

__device__ __forceinline__ void load_g2l16(const unsigned short* g, unsigned short* l) {
    __builtin_amdgcn_global_load_lds(
        (const __attribute__((address_space(1))) unsigned int*)g,
        (__attribute__((address_space(3))) unsigned int*)l,
        16 /*bytes*/, 0 /*offset*/, 0 /*aux*/);
}

// ---------------------------------------------------------------------------
// Weight prep, one launch:
//  blocks [0,768):  pack Wq/Wk/Wv [h][m][d] fp32 -> Wt[n=h*64+d][k=m] bf16
//  blocks [768,1792): straight cast Wo (1M floats) -> bf16
__global__ __launch_bounds__(256) void prep_w(const float* __restrict__ W0,
                                              const float* __restrict__ W1,
                                              const float* __restrict__ W2,
                                              const float* __restrict__ Wo,
                                              unsigned short* __restrict__ T0,
                                              unsigned short* __restrict__ T1,
                                              unsigned short* __restrict__ T2,
                                              unsigned short* __restrict__ To) {
    __shared__ float tile[64][68];
    int blk = blockIdx.x;
    int t = threadIdx.x;
    if (blk < 768) {
        int w = blk >> 8, h = (blk >> 4) & 15, mb = blk & 15;
        const float* W = w == 0 ? W0 : (w == 1 ? W1 : W2);
        unsigned short* T = w == 0 ? T0 : (w == 1 ? T1 : T2);
        #pragma unroll
        for (int i = 0; i < 4; ++i) {
            int f = t + 256 * i;            // 0..1023
            int m = f >> 4, dg = (f & 15) * 4;
            *(float4*)&tile[m][dg] = *(const float4*)&W[((size_t)(h * 16 + mb) * 64 + m) * 64 + dg];
        }
        __syncthreads();
        #pragma unroll
        for (int i = 0; i < 2; ++i) {
            int f = t + 256 * i;            // 0..511
            int d = f >> 3, mg = f & 7;
            ushort4 a, b;
            a.x = f2bf(tile[mg * 8 + 0][d]); a.y = f2bf(tile[mg * 8 + 1][d]);
            a.z = f2bf(tile[mg * 8 + 2][d]); a.w = f2bf(tile[mg * 8 + 3][d]);
            b.x = f2bf(tile[mg * 8 + 4][d]); b.y = f2bf(tile[mg * 8 + 5][d]);
            b.z = f2bf(tile[mg * 8 + 6][d]); b.w = f2bf(tile[mg * 8 + 7][d]);
            unsigned short* dst = T + (size_t)(h * 64 + d) * DMODEL + mb * 64 + mg * 8;
            *(ushort4*)dst = a; *(ushort4*)(dst + 4) = b;
        }
    } else {
        int i = (blk - 768) * 256 + t;      // < 262144 float4 groups
        float4 v = ((const float4*)Wo)[i];
        ushort4 o;
        o.x = f2bf(v.x); o.y = f2bf(v.y); o.z = f2bf(v.z); o.w = f2bf(v.w);
        ((ushort4*)To)[i] = o;
    }
}

// ---------------------------------------------------------------------------
// Core: C[64x128 tile] = A[M,K] * B^T, B is [N,K] bf16 (K contiguous).
// BK=64, 4 waves each 32x64 via 2x4 of 16x16x32 MFMA.
// XOR swizzle: LDS slot (row, s) holds global k-group s ^ (row&7).
// AF32: A is fp32 in global; convert to bf16 during LDS staging (fused cast).
// OBF16: store bf16 instead of fp32. sm: fused 64-wide head-group softmax.
template <bool OBF16, bool AF32>
__device__ __forceinline__ void gemm_core(const void* __restrict__ Av,
                                          const unsigned short* __restrict__ Bp,
                                          void* __restrict__ Cv,
                                          int K, int N, int bm0, int bn0, bool sm) {
    __shared__ unsigned short ldsA[64 * 64];    // 8 KB
    __shared__ unsigned short ldsB[128 * 64];   // 16 KB

    const int t    = threadIdx.x;
    const int lane = t & 63;
    const int wave = t >> 6;
    const int wm   = (wave & 1) * 32;
    const int wn   = (wave >> 1) * 64;
    const int fr   = lane & 15;
    const int quad = lane >> 4;

    const float*          A32 = (const float*)Av;
    const unsigned short* A16 = (const unsigned short*)Av;

    f32x4 acc[2][4] = {};

    // staging source addressing (global kg permuted by row&7; LDS dest linear)
    size_t offA[2];
    #pragma unroll
    for (int i = 0; i < 2; ++i) {
        int f = t + 256 * i, row = f >> 3, kg = (f & 7) ^ (row & 7);
        offA[i] = (size_t)(bm0 + row) * K + kg * 8;
    }
    const unsigned short* gB[4];
    #pragma unroll
    for (int i = 0; i < 4; ++i) {
        int f = t + 256 * i, row = f >> 3, kg = (f & 7) ^ (row & 7);
        gB[i] = Bp + (size_t)(bn0 + row) * K + kg * 8;
    }

    for (int k0 = 0; k0 < K; k0 += 64) {
        if (AF32) {
            #pragma unroll
            for (int i = 0; i < 2; ++i) {
                const float* src = A32 + offA[i] + k0;
                float4 lo = *(const float4*)src;
                float4 hi = *(const float4*)(src + 4);
                uint4 pk;
                pk.x = cvt_pk_bf16(lo.x, lo.y);
                pk.y = cvt_pk_bf16(lo.z, lo.w);
                pk.z = cvt_pk_bf16(hi.x, hi.y);
                pk.w = cvt_pk_bf16(hi.z, hi.w);
                *(uint4*)&ldsA[(t + 256 * i) * 8] = pk;
            }
        } else {
            #pragma unroll
            for (int i = 0; i < 2; ++i)
                load_g2l16(A16 + offA[i] + k0, &ldsA[(t + 256 * i) * 8]);
        }
        #pragma unroll
        for (int i = 0; i < 4; ++i)
            load_g2l16(gB[i] + k0, &ldsB[(t + 256 * i) * 8]);
        asm volatile("s_waitcnt vmcnt(0)" ::: "memory");
        __syncthreads();

        bf16x8 af[2][2], bfr[4][2];
        #pragma unroll
        for (int i = 0; i < 2; ++i) {
            int row = wm + i * 16 + fr;
            #pragma unroll
            for (int kh = 0; kh < 2; ++kh) {
                int s = (kh * 4 + quad) ^ (row & 7);
                af[i][kh] = *reinterpret_cast<const bf16x8*>(&ldsA[row * 64 + s * 8]);
            }
        }
        #pragma unroll
        for (int j = 0; j < 4; ++j) {
            int row = wn + j * 16 + fr;
            #pragma unroll
            for (int kh = 0; kh < 2; ++kh) {
                int s = (kh * 4 + quad) ^ (row & 7);
                bfr[j][kh] = *reinterpret_cast<const bf16x8*>(&ldsB[row * 64 + s * 8]);
            }
        }

        #pragma unroll
        for (int kh = 0; kh < 2; ++kh)
            #pragma unroll
            for (int i = 0; i < 2; ++i)
                #pragma unroll
                for (int j = 0; j < 4; ++j)
                    acc[i][j] = __builtin_amdgcn_mfma_f32_16x16x32_bf16(af[i][kh], bfr[j][kh], acc[i][j], 0, 0, 0);

        __syncthreads();
    }

    // C/D layout: col = lane&15 (fr), row = quad*4 + reg
    #pragma unroll
    for (int i = 0; i < 2; ++i) {
        #pragma unroll
        for (int r = 0; r < 4; ++r) {
            float v[4];
            #pragma unroll
            for (int j = 0; j < 4; ++j) v[j] = acc[i][j][r];
            if (sm) {
                #pragma unroll
                for (int j = 0; j < 4; ++j) v[j] *= INV_DSCALE;
                float m = fmaxf(fmaxf(v[0], v[1]), fmaxf(v[2], v[3]));
                #pragma unroll
                for (int off = 8; off; off >>= 1) m = fmaxf(m, __shfl_xor(m, off, 16));
                float s = 0.f;
                #pragma unroll
                for (int j = 0; j < 4; ++j) { v[j] = __expf(v[j] - m); s += v[j]; }
                #pragma unroll
                for (int off = 8; off; off >>= 1) s += __shfl_xor(s, off, 16);
                float inv = 1.0f / s;
                #pragma unroll
                for (int j = 0; j < 4; ++j) v[j] *= inv;
            }
            int rr = bm0 + wm + i * 16 + quad * 4 + r;
            size_t base = (size_t)rr * N + bn0 + wn + fr;
            if (OBF16) {
                unsigned short* C = (unsigned short*)Cv;
                #pragma unroll
                for (int j = 0; j < 4; ++j) C[base + j * 16] = f2bf(v[j]);
            } else {
                float* C = (float*)Cv;
                #pragma unroll
                for (int j = 0; j < 4; ++j) C[base + j * 16] = v[j];
            }
        }
    }
}

// Three projection GEMMs in one launch: z selects tensor; softmax for z<2 (Q,K).
__global__ __launch_bounds__(256, 4) void proj3(const float* __restrict__ xq,
                                                const float* __restrict__ xk,
                                                const float* __restrict__ xv,
                                                const unsigned short* __restrict__ wq,
                                                const unsigned short* __restrict__ wk,
                                                const unsigned short* __restrict__ wv,
                                                unsigned short* __restrict__ Qb,
                                                unsigned short* __restrict__ Kb,
                                                unsigned short* __restrict__ Vb) {
    int z = blockIdx.z;
    const float* A = z == 0 ? xq : (z == 1 ? xk : xv);
    const unsigned short* B = z == 0 ? wq : (z == 1 ? wk : wv);
    unsigned short* C = z == 0 ? Qb : (z == 1 ? Kb : Vb);
    gemm_core<true, true>(A, B, C, DMODEL, DMODEL, blockIdx.x * 64, blockIdx.y * 128, z < 2);
}

// out = R (bf16 [8192,1024]) @ Wo^T -> fp32
__global__ __launch_bounds__(256, 4) void gemm_out(const unsigned short* __restrict__ R,
                                                   const unsigned short* __restrict__ Wo,
                                                   float* __restrict__ out) {
    gemm_core<false, false>(R, Wo, out, DMODEL, DMODEL, blockIdx.x * 64, blockIdx.y * 128, false);
}

// ---------------------------------------------------------------------------
// P[chunk][bh][d][e] = sum over 128 s of Ks[b,s,h,d] * V[b,s,h,e]  (fp32 out,
// bf16 in). grid: bh*16 + chunk (1024 blocks), 32 KB LDS.
__global__ __launch_bounds__(256) void kv_outer(const unsigned short* __restrict__ Ks,
                                                const unsigned short* __restrict__ V,
                                                float* __restrict__ P) {
    __shared__ float sk[64][64];
    __shared__ float sv[64][64];
    int bh = blockIdx.x >> 4, chunk = blockIdx.x & 15;
    int b = bh >> 4, h = bh & 15;
    int t = threadIdx.x;
    int d = t & 63, eg = t >> 6;
    int e0 = eg * 16;
    float acc[16];
    #pragma unroll
    for (int j = 0; j < 16; ++j) acc[j] = 0.f;

    for (int sc = 0; sc < 2; ++sc) {
        int s0 = chunk * 128 + sc * 64;
        #pragma unroll
        for (int i = 0; i < 2; ++i) {
            int f = t + 256 * i;        // 0..511
            int r = f >> 3, c = (f & 7) * 8;
            size_t g = (size_t)(b * SEQ + s0 + r) * DMODEL + h * DHEAD + c;
            u16x8 kk = *(const u16x8*)&Ks[g];
            u16x8 vv = *(const u16x8*)&V[g];
            #pragma unroll
            for (int j = 0; j < 8; ++j) { sk[r][c + j] = bf2f(kk[j]); sv[r][c + j] = bf2f(vv[j]); }
        }
        __syncthreads();
        #pragma unroll 8
        for (int s = 0; s < 64; ++s) {
            float kd = sk[s][d];
            float4 v0 = *(const float4*)&sv[s][e0];
            float4 v1 = *(const float4*)&sv[s][e0 + 4];
            float4 v2 = *(const float4*)&sv[s][e0 + 8];
            float4 v3 = *(const float4*)&sv[s][e0 + 12];
            acc[0]  += kd * v0.x; acc[1]  += kd * v0.y; acc[2]  += kd * v0.z; acc[3]  += kd * v0.w;
            acc[4]  += kd * v1.x; acc[5]  += kd * v1.y; acc[6]  += kd * v1.z; acc[7]  += kd * v1.w;
            acc[8]  += kd * v2.x; acc[9]  += kd * v2.y; acc[10] += kd * v2.z; acc[11] += kd * v2.w;
            acc[12] += kd * v3.x; acc[13] += kd * v3.y; acc[14] += kd * v3.z; acc[15] += kd * v3.w;
        }
        __syncthreads();
    }
    float* Pp = P + ((size_t)chunk * 64 + bh) * 4096 + d * 64 + e0;
    #pragma unroll
    for (int j = 0; j < 16; j += 4)
        *(float4*)&Pp[j] = make_float4(acc[j], acc[j + 1], acc[j + 2], acc[j + 3]);
}

// A[idx] = sum over 16 chunks of P[chunk][idx], idx in [0, 64*4096)
__global__ __launch_bounds__(256) void reduce_A(const float* __restrict__ P,
                                                float* __restrict__ A) {
    int idx = blockIdx.x * 256 + threadIdx.x;   // 0 .. 262143
    float s = 0.f;
    #pragma unroll
    for (int c = 0; c < 16; ++c) s += P[(size_t)c * (64 * 4096) + idx];
    A[idx] = s;
}

// ---------------------------------------------------------------------------
// Bt[b,h,s,e] = sum_d Qs[b,s,h,d] * A[bh][d][e]; Qs bf16, A fp32; bf16 out in
// [b,h,s,e] flat order. grid: bh*32 + sb (sb covers 64 s rows)
__global__ __launch_bounds__(256) void qs_a(const unsigned short* __restrict__ Qs,
                                            const float* __restrict__ A,
                                            unsigned short* __restrict__ R) {
    __shared__ float sA[64][64];
    __shared__ float sQ[64][64];
    int bh = blockIdx.x >> 5, sb = blockIdx.x & 31;
    int b = bh >> 4, h = bh & 15;
    int t = threadIdx.x;
    #pragma unroll
    for (int i = 0; i < 4; ++i) {
        int f = t + 256 * i;            // float4 slot, 1024 total
        int r = f >> 4, c = (f & 15) * 4;
        *(float4*)&sA[r][c] = *(const float4*)&A[(size_t)bh * 4096 + (size_t)f * 4];
    }
    #pragma unroll
    for (int i = 0; i < 2; ++i) {
        int f = t + 256 * i;            // 0..511
        int r = f >> 3, c = (f & 7) * 8;
        u16x8 q = *(const u16x8*)&Qs[(size_t)(b * SEQ + sb * 64 + r) * DMODEL + h * DHEAD + c];
        #pragma unroll
        for (int j = 0; j < 8; ++j) sQ[r][c + j] = bf2f(q[j]);
    }
    __syncthreads();
    int lane = t & 63, w = t >> 6;
    float acc[16];
    #pragma unroll
    for (int r = 0; r < 16; ++r) acc[r] = 0.f;
    for (int d2 = 0; d2 < 64; d2 += 4) {
        float a0 = sA[d2][lane], a1 = sA[d2 + 1][lane];
        float a2 = sA[d2 + 2][lane], a3 = sA[d2 + 3][lane];
        #pragma unroll
        for (int r = 0; r < 16; ++r) {
            float4 q4 = *(const float4*)&sQ[w * 16 + r][d2];   // wave-broadcast
            acc[r] += q4.x * a0 + q4.y * a1 + q4.z * a2 + q4.w * a3;
        }
    }
    size_t base = (size_t)bh * (SEQ * DHEAD) + (size_t)(sb * 64 + w * 16) * DHEAD + lane;
    #pragma unroll
    for (int r = 0; r < 16; ++r) R[base + (size_t)r * DHEAD] = f2bf(acc[r]);
}

// ---------------------------------------------------------------------------
extern "C" void kernel_launch(void* const* d_in, const int* in_sizes, int n_in,
                              void* d_out, int out_size, void* d_ws, size_t ws_size,
                              hipStream_t stream) {
    const float* xq = (const float*)d_in[0];
    const float* xk = (const float*)d_in[1];
    const float* xv = (const float*)d_in[2];
    const float* Wq = (const float*)d_in[3];
    const float* Wk = (const float*)d_in[4];
    const float* Wv = (const float*)d_in[5];
    const float* Wo = (const float*)d_in[6];
    float* out = (float*)d_out;
    char* ws = (char*)d_ws;

    const size_t MB = 1ull << 20;
    unsigned short* wq_t = (unsigned short*)(ws + 0 * MB);    // 2 MB each
    unsigned short* wk_t = (unsigned short*)(ws + 2 * MB);
    unsigned short* wv_t = (unsigned short*)(ws + 4 * MB);
    unsigned short* wo_b = (unsigned short*)(ws + 6 * MB);    // 2 MB
    unsigned short* Qb = (unsigned short*)(ws + 8 * MB);      // bf16, 16 MB each
    unsigned short* Kb = (unsigned short*)(ws + 24 * MB);
    unsigned short* Vb = (unsigned short*)(ws + 40 * MB);
    float* Am = (float*)(ws + 56 * MB);                       // 1 MB
    unsigned short* R = (unsigned short*)(ws + 57 * MB);      // 16 MB
    float* P = (float*)(ws + 73 * MB);                        // 16 MB

    // weights -> bf16 (Wq/Wk/Wv packed N x K via LDS transpose; Wo straight)
    prep_w<<<1792, 256, 0, stream>>>(Wq, Wk, Wv, Wo, wq_t, wk_t, wv_t, wo_b);

    // projections with fused fp32->bf16 A-staging; softmax fused for Q,K; bf16 out
    proj3<<<dim3(ROWS / 64, DMODEL / 128, 3), 256, 0, stream>>>(
        xq, xk, xv, wq_t, wk_t, wv_t, Qb, Kb, Vb);

    // A = softmax(K)^T V per (b,h): split-S partials then deterministic reduce
    kv_outer<<<BATCH * HEADS * 16, 256, 0, stream>>>(Kb, Vb, P);
    reduce_A<<<1024, 256, 0, stream>>>(P, Am);

    // Bt = softmax(Q) A -> bf16 R in [b,h,s,d] flat order (== reference reshape)
    qs_a<<<BATCH * HEADS * 32, 256, 0, stream>>>(Qb, Am, R);

    // out = R @ W_O^T  (fp32 out)
    gemm_out<<<dim3(ROWS / 64, DMODEL / 128), 256, 0, stream>>>(R, wo_b, out);
}